// Round 1
// baseline (64.162 us; speedup 1.0000x reference)
//
#include <hip/hip_runtime.h>

// Problem constants (B=8, C=128, H=W=48 -> N=2304)
#define NTOK 2304
#define CC   128
#define BT   128   // block tile (M and N)

typedef __attribute__((ext_vector_type(8))) short bf16x8;
typedef __attribute__((ext_vector_type(4))) float f32x4;

// round-to-nearest-even fp32 -> bf16
__device__ __forceinline__ unsigned short f2bf(float f) {
  unsigned int u = __builtin_bit_cast(unsigned int, f);
  u += 0x7FFFu + ((u >> 16) & 1u);
  return (unsigned short)(u >> 16);
}

// Prep: exact fp32 squared norms of every column of x and y.
// sx[b][n] = sum_c x[b][c][n]^2 ; sy likewise for y.
__global__ __launch_bounds__(256) void pwd_prep_norms(
    const float* __restrict__ x, const float* __restrict__ y,
    float* __restrict__ sx, float* __restrict__ sy) {
  const int n = blockIdx.x * 256 + threadIdx.x;   // 0..2303
  const int b = blockIdx.y;                        // 0..7
  const float* src = blockIdx.z ? y : x;
  float* dst = blockIdx.z ? sy : sx;
  const float* p = src + (size_t)b * CC * NTOK + n;
  float s = 0.f;
#pragma unroll 8
  for (int c = 0; c < CC; ++c) {
    float v = p[(size_t)c * NTOK];
    s = fmaf(v, v, s);
  }
  dst[b * NTOK + n] = s;
}

// Main: out[b][i][j] = sx[b][i] + sy[b][j] - 2 * sum_c y[b][c][i]*x[b][c][j]
// A (M side, rows i)  = y columns  -> LDS [m][k] bf16, K contiguous, swizzled
// B (N side, cols j)  = x columns  -> LDS [n][k] bf16, K contiguous, swizzled
__global__ __launch_bounds__(256, 2) void pwd_gemm(
    const float* __restrict__ x, const float* __restrict__ y,
    const float* __restrict__ sx, const float* __restrict__ sy,
    float* __restrict__ out) {
  __shared__ __attribute__((aligned(16))) char smem[2 * 32768 + 1024];
  char* smA = smem;           // 128 rows * 256 B (128 bf16)
  char* smB = smem + 32768;
  float* s_sx = (float*)(smem + 65536);         // 128 floats
  float* s_sy = (float*)(smem + 65536 + 512);   // 128 floats

  const int tid = threadIdx.x;
  const int b  = blockIdx.z;
  const int i0 = blockIdx.y * BT;   // output rows
  const int j0 = blockIdx.x * BT;   // output cols

  // ---------------- staging: global fp32 [k][n] -> LDS bf16 [n][k] ----------
  // thread t handles tile-column c = t&127, k-half kh = t>>7.
  {
    const int c  = tid & 127;
    const int kh = tid >> 7;
    const float* srcA = y + (size_t)b * CC * NTOK + i0 + c;
    const float* srcB = x + (size_t)b * CC * NTOK + j0 + c;
    char* dA = smA + c * 256;
    char* dB = smB + c * 256;
    const int cx = c & 15;
#pragma unroll
    for (int oct = 0; oct < 8; ++oct) {
      const int o  = kh * 8 + oct;     // 16B-slot index 0..15 (8 bf16 of k)
      const int k0 = o * 8;
      float va[8], vb[8];
#pragma unroll
      for (int e = 0; e < 8; ++e) {
        va[e] = srcA[(size_t)(k0 + e) * NTOK];
        vb[e] = srcB[(size_t)(k0 + e) * NTOK];
      }
      uint4 wa, wb;
      wa.x = (unsigned)f2bf(va[0]) | ((unsigned)f2bf(va[1]) << 16);
      wa.y = (unsigned)f2bf(va[2]) | ((unsigned)f2bf(va[3]) << 16);
      wa.z = (unsigned)f2bf(va[4]) | ((unsigned)f2bf(va[5]) << 16);
      wa.w = (unsigned)f2bf(va[6]) | ((unsigned)f2bf(va[7]) << 16);
      wb.x = (unsigned)f2bf(vb[0]) | ((unsigned)f2bf(vb[1]) << 16);
      wb.y = (unsigned)f2bf(vb[2]) | ((unsigned)f2bf(vb[3]) << 16);
      wb.z = (unsigned)f2bf(vb[4]) | ((unsigned)f2bf(vb[5]) << 16);
      wb.w = (unsigned)f2bf(vb[6]) | ((unsigned)f2bf(vb[7]) << 16);
      const int slot = (o ^ cx) << 4;       // XOR swizzle, 16B granules
      *(uint4*)(dA + slot) = wa;
      *(uint4*)(dB + slot) = wb;
    }
  }
  if (tid < 128) s_sx[tid] = sx[b * NTOK + i0 + tid];
  else           s_sy[tid - 128] = sy[b * NTOK + j0 + (tid - 128)];
  __syncthreads();

  // ---------------- compute: 4 waves in 2x2, each 64x64 ---------------------
  const int l  = tid & 63;
  const int w  = tid >> 6;
  const int wm = (w >> 1) * 64;
  const int wn = (w & 1) * 64;
  const int lr = l & 15;   // fragment row/col within 16
  const int lg = l >> 4;   // k-group 0..3

  f32x4 acc[4][4] = {};
#pragma unroll
  for (int ks = 0; ks < 4; ++ks) {
    bf16x8 af[4], bfr[4];
    const int o = ks * 4 + lg;           // 16B slot (8 k's)
#pragma unroll
    for (int mf = 0; mf < 4; ++mf) {
      const int row = wm + mf * 16 + lr;
      af[mf] = *(const bf16x8*)(smA + row * 256 + ((o ^ (row & 15)) << 4));
    }
#pragma unroll
    for (int nf = 0; nf < 4; ++nf) {
      const int col = wn + nf * 16 + lr;
      bfr[nf] = *(const bf16x8*)(smB + col * 256 + ((o ^ (col & 15)) << 4));
    }
#pragma unroll
    for (int mf = 0; mf < 4; ++mf)
#pragma unroll
      for (int nf = 0; nf < 4; ++nf)
        acc[mf][nf] = __builtin_amdgcn_mfma_f32_16x16x32_bf16(
            af[mf], bfr[nf], acc[mf][nf], 0, 0, 0);
  }

  // ---------------- epilogue: P = sx[i] + sy[j] - 2*zz ----------------------
#pragma unroll
  for (int mf = 0; mf < 4; ++mf) {
#pragma unroll
    for (int nf = 0; nf < 4; ++nf) {
      const int col = wn + nf * 16 + lr;          // local j
      const float syv = s_sy[col];
      const size_t jg = (size_t)(j0 + col);
#pragma unroll
      for (int r = 0; r < 4; ++r) {
        const int row = wm + mf * 16 + lg * 4 + r; // local i (C/D layout m89)
        const float v = s_sx[row] + syv - 2.0f * acc[mf][nf][r];
        out[((size_t)b * NTOK + (i0 + row)) * NTOK + jg] = v;
      }
    }
  }
}

extern "C" void kernel_launch(void* const* d_in, const int* in_sizes, int n_in,
                              void* d_out, int out_size, void* d_ws, size_t ws_size,
                              hipStream_t stream) {
  (void)in_sizes; (void)n_in; (void)out_size; (void)ws_size;
  const float* x = (const float*)d_in[0];
  const float* y = (const float*)d_in[1];
  float* out = (float*)d_out;
  float* sx = (float*)d_ws;              // 8*2304 fp32
  float* sy = sx + 8 * NTOK;             // 8*2304 fp32  (total 147,456 B of ws)

  dim3 gp(NTOK / 256, 8, 2);
  pwd_prep_norms<<<gp, dim3(256), 0, stream>>>(x, y, sx, sy);

  dim3 gg(NTOK / BT, NTOK / BT, 8);
  pwd_gemm<<<gg, dim3(256), 0, stream>>>(x, y, sx, sy, out);
}